// Round 4
// baseline (53.334 us; speedup 1.0000x reference)
//
#include <hip/hip_runtime.h>
#include <math.h>

#define NN 8192
#define ROWS_PER_WAVE 4
#define WAVES_PER_BLOCK 4   // block = 256 threads, 16 rows/block, grid = 512

typedef float f32x4 __attribute__((ext_vector_type(4)));

__global__ __launch_bounds__(256, 2)
void lif_r_kernel(const float* __restrict__ x_in,
                  const float* __restrict__ v,
                  const float* __restrict__ g,
                  const float* __restrict__ theta_s,
                  const float* __restrict__ w,
                  const float* __restrict__ E_L,
                  const float* __restrict__ C_m,
                  const float* __restrict__ Gc,
                  const float* __restrict__ tau_g,
                  float* __restrict__ out)
{
    const int wave = threadIdx.x >> 6;      // 0..3
    const int lane = threadIdx.x & 63;
    const int row0 = (blockIdx.x * WAVES_PER_BLOCK + wave) * ROWS_PER_WAVE;

    const f32x4* __restrict__ g4 = reinterpret_cast<const f32x4*>(g);
    const f32x4* __restrict__ wr0 = reinterpret_cast<const f32x4*>(w + (size_t)(row0 + 0) * NN);
    const f32x4* __restrict__ wr1 = reinterpret_cast<const f32x4*>(w + (size_t)(row0 + 1) * NN);
    const f32x4* __restrict__ wr2 = reinterpret_cast<const f32x4*>(w + (size_t)(row0 + 2) * NN);
    const f32x4* __restrict__ wr3 = reinterpret_cast<const f32x4*>(w + (size_t)(row0 + 3) * NN);

    float acc0 = 0.0f, acc1 = 0.0f, acc2 = 0.0f, acc3 = 0.0f;

    // 2048 float4 chunks per row / 64 lanes = 32 steps; unroll 4 =>
    // 16 w-loads + 4 g-loads in flight (~85 load VGPRs), no spill at 256 cap.
    for (int t = 0; t < 8; ++t) {
#pragma unroll
        for (int u = 0; u < 4; ++u) {
            const int idx = lane + 64 * (t * 4 + u);
            const f32x4 gv = g4[idx];     // loaded ONCE, reused for 4 rows
            const f32x4 a = wr0[idx];
            const f32x4 b = wr1[idx];
            const f32x4 c = wr2[idx];
            const f32x4 d = wr3[idx];
            acc0 += a.x * gv.x + a.y * gv.y + a.z * gv.z + a.w * gv.w;
            acc1 += b.x * gv.x + b.y * gv.y + b.z * gv.z + b.w * gv.w;
            acc2 += c.x * gv.x + c.y * gv.y + c.z * gv.z + c.w * gv.w;
            acc3 += d.x * gv.x + d.y * gv.y + d.z * gv.z + d.w * gv.w;
        }
    }

    // 64-lane tree reductions (4 independent)
#pragma unroll
    for (int off = 32; off > 0; off >>= 1) {
        acc0 += __shfl_down(acc0, off, 64);
        acc1 += __shfl_down(acc1, off, 64);
        acc2 += __shfl_down(acc2, off, 64);
        acc3 += __shfl_down(acc3, off, 64);
    }

    if (lane == 0) {
        const float accs[4] = {acc0, acc1, acc2, acc3};
#pragma unroll
        for (int r = 0; r < 4; ++r) {
            const int row = row0 + r;
            const float I      = accs[r] + x_in[row];
            const float vv     = v[row];
            const float el     = E_L[row];
            const float th     = theta_s[row];
            const float dv     = (Gc[row] * (el - vv) + I * 18.0f) / C_m[row];
            const float v_next = vv + dv;
            const float dlt    = v_next - th;
            const float spk_soft = 1.0f / (1.0f + expf(-dlt));
            const float spiked   = (v_next >= th) ? 1.0f : 0.0f;
            const float v_reset  = el + 0.12f * (vv - el) - 12.0f;
            const float v_new    = spiked * v_reset + (1.0f - spiked) * v_next;
            out[row]      = v_new;     // output 0: v_new
            out[NN + row] = spk_soft;  // output 1: spiked_soft
        }
        (void)tau_g;                   // hidden-state update discarded
    }
}

extern "C" void kernel_launch(void* const* d_in, const int* in_sizes, int n_in,
                              void* d_out, int out_size, void* d_ws, size_t ws_size,
                              hipStream_t stream)
{
    const float* x_in    = (const float*)d_in[0];
    const float* v       = (const float*)d_in[1];
    const float* g       = (const float*)d_in[2];
    const float* theta_s = (const float*)d_in[3];
    const float* w       = (const float*)d_in[4];
    const float* E_L     = (const float*)d_in[5];
    const float* C_m     = (const float*)d_in[6];
    const float* Gc      = (const float*)d_in[7];
    const float* tau_g   = (const float*)d_in[8];
    float* out = (float*)d_out;

    dim3 grid(NN / (ROWS_PER_WAVE * WAVES_PER_BLOCK));  // 512 blocks, 2/CU
    dim3 block(256);
    lif_r_kernel<<<grid, block, 0, stream>>>(x_in, v, g, theta_s, w,
                                             E_L, C_m, Gc, tau_g, out);
}

// Round 5
// 43.771 us; speedup vs baseline: 1.2185x; 1.2185x over previous
//
#include <hip/hip_runtime.h>
#include <math.h>

#define NN 8192
#define ROWS_PER_BLOCK 4

typedef float f32x4 __attribute__((ext_vector_type(4)));

__global__ __launch_bounds__(256, 4)
void lif_r_kernel(const float* __restrict__ x_in,
                  const float* __restrict__ v,
                  const float* __restrict__ g,
                  const float* __restrict__ theta_s,
                  const float* __restrict__ w,
                  const float* __restrict__ E_L,
                  const float* __restrict__ C_m,
                  const float* __restrict__ Gc,
                  const float* __restrict__ tau_g,
                  float* __restrict__ out)
{
    const int wave = threadIdx.x >> 6;      // 0..3
    const int lane = threadIdx.x & 63;
    const int row  = blockIdx.x * ROWS_PER_BLOCK + wave;

    const f32x4* __restrict__ wrow =
        reinterpret_cast<const f32x4*>(w + (size_t)row * NN);
    const f32x4* __restrict__ g4 = reinterpret_cast<const f32x4*>(g);

    // One row per wave (R1 structure). Unroll 8 inside a loop of 4 so the
    // in-flight load set (~8 f32x4 w + 8 f32x4 g = 64 VGPRs) fits the
    // 128-VGPR cap implied by 4 waves/SIMD. ONLY change vs R1: occupancy.
    float acc = 0.0f;
    for (int t = 0; t < 4; ++t) {
#pragma unroll
        for (int u = 0; u < 8; ++u) {
            const int idx = lane + 64 * (t * 8 + u);
            const f32x4 wv = wrow[idx];   // cached stream (NT hurt in R3)
            const f32x4 gv = g4[idx];     // g is hot in L1/L2
            acc += wv.x * gv.x + wv.y * gv.y + wv.z * gv.z + wv.w * gv.w;
        }
    }

    // 64-lane tree reduction
#pragma unroll
    for (int off = 32; off > 0; off >>= 1)
        acc += __shfl_down(acc, off, 64);

    if (lane == 0) {
        const float I      = acc + x_in[row];
        const float vv     = v[row];
        const float el     = E_L[row];
        const float th     = theta_s[row];
        const float dv     = (Gc[row] * (el - vv) + I * 18.0f) / C_m[row];
        const float v_next = vv + dv;
        const float d      = v_next - th;
        const float spk_soft = 1.0f / (1.0f + expf(-d));
        const float spiked   = (v_next >= th) ? 1.0f : 0.0f;
        const float v_reset  = el + 0.12f * (vv - el) - 12.0f;
        const float v_new    = spiked * v_reset + (1.0f - spiked) * v_next;
        out[row]      = v_new;     // output 0: v_new
        out[NN + row] = spk_soft;  // output 1: spiked_soft
        (void)tau_g;               // hidden-state update discarded
    }
}

extern "C" void kernel_launch(void* const* d_in, const int* in_sizes, int n_in,
                              void* d_out, int out_size, void* d_ws, size_t ws_size,
                              hipStream_t stream)
{
    const float* x_in    = (const float*)d_in[0];
    const float* v       = (const float*)d_in[1];
    const float* g       = (const float*)d_in[2];
    const float* theta_s = (const float*)d_in[3];
    const float* w       = (const float*)d_in[4];
    const float* E_L     = (const float*)d_in[5];
    const float* C_m     = (const float*)d_in[6];
    const float* Gc      = (const float*)d_in[7];
    const float* tau_g   = (const float*)d_in[8];
    float* out = (float*)d_out;

    dim3 grid(NN / ROWS_PER_BLOCK);   // 2048 blocks
    dim3 block(256);
    lif_r_kernel<<<grid, block, 0, stream>>>(x_in, v, g, theta_s, w,
                                             E_L, C_m, Gc, tau_g, out);
}